// Round 1
// baseline (217.316 us; speedup 1.0000x reference)
//
#include <hip/hip_runtime.h>
#include <math.h>

// Problem constants
#define NJ   24
#define JD   3
#define TS   120
#define B_TOT 16384
#define CT   (NJ * JD * TS)   // 8640 (c,t) positions per batch row
#define CT4  (CT / 4)         // 2160 float4 positions
#define NCHUNK 128            // batch chunks
#define BPC  (B_TOT / NCHUNK) // 128 batches per chunk

__global__ void pj_zero(float* __restrict__ sq) {
    int i = blockIdx.x * blockDim.x + threadIdx.x;
    if (i < CT) sq[i] = 0.0f;
}

__global__ void pj_accum(const float* __restrict__ src,
                         const float* __restrict__ tgt,
                         float* __restrict__ sq) {
    int p4 = blockIdx.x * blockDim.x + threadIdx.x;   // float4 position in [0, CT4)
    if (p4 >= CT4) return;
    const float4* s = (const float4*)src;
    const float4* t = (const float4*)tgt;
    long base = (long)blockIdx.y * BPC * CT4 + p4;
    float ax = 0.f, ay = 0.f, az = 0.f, aw = 0.f;
    #pragma unroll 4
    for (int b = 0; b < BPC; ++b) {
        float4 a = s[base];
        float4 c = t[base];
        float dx = a.x - c.x, dy = a.y - c.y, dz = a.z - c.z, dw = a.w - c.w;
        ax += dx * dx; ay += dy * dy; az += dz * dz; aw += dw * dw;
        base += CT4;
    }
    atomicAdd(&sq[p4 * 4 + 0], ax);
    atomicAdd(&sq[p4 * 4 + 1], ay);
    atomicAdd(&sq[p4 * 4 + 2], az);
    atomicAdd(&sq[p4 * 4 + 3], aw);
}

__global__ void pj_finalize(const float* __restrict__ sq, float* __restrict__ out) {
    float local = 0.0f;
    // 2880 (n,t) cells; each sums 3 joint-dim rows then sqrt
    for (int i = threadIdx.x; i < NJ * TS; i += blockDim.x) {
        int n = i / TS, t = i - (i / TS) * TS;
        float s = sq[(3 * n + 0) * TS + t]
                + sq[(3 * n + 1) * TS + t]
                + sq[(3 * n + 2) * TS + t];
        local += sqrtf(s);
    }
    // wave reduce (64 lanes)
    for (int off = 32; off > 0; off >>= 1)
        local += __shfl_down(local, off, 64);
    __shared__ float red[4];
    int lane = threadIdx.x & 63, wid = threadIdx.x >> 6;
    if (lane == 0) red[wid] = local;
    __syncthreads();
    if (threadIdx.x == 0) {
        float tot = 0.f;
        int nw = blockDim.x >> 6;
        for (int w = 0; w < nw; ++w) tot += red[w];
        out[0] = tot;
    }
}

extern "C" void kernel_launch(void* const* d_in, const int* in_sizes, int n_in,
                              void* d_out, int out_size, void* d_ws, size_t ws_size,
                              hipStream_t stream) {
    const float* src = (const float*)d_in[0];
    const float* tgt = (const float*)d_in[1];
    float* sq = (float*)d_ws;          // 8640 floats = 34.6 KB scratch
    float* out = (float*)d_out;

    pj_zero<<<(CT + 255) / 256, 256, 0, stream>>>(sq);

    dim3 grid((CT4 + 255) / 256, NCHUNK);
    pj_accum<<<grid, 256, 0, stream>>>(src, tgt, sq);

    pj_finalize<<<1, 256, 0, stream>>>(sq, out);
}

// Round 2
// 216.426 us; speedup vs baseline: 1.0041x; 1.0041x over previous
//
#include <hip/hip_runtime.h>
#include <math.h>

// Problem constants
#define NJ   24
#define JD   3
#define TS   120
#define B_TOT 16384
#define CT   (NJ * JD * TS)   // 8640 (c,t) positions per batch row
#define CT4  (CT / 4)         // 2160 float4 positions
#define NCHUNK 512            // batch chunks (4608 blocks -> ~18/CU, small tail)
#define BPC  (B_TOT / NCHUNK) // 32 batches per chunk

__global__ void pj_zero(float* __restrict__ sq) {
    int i = blockIdx.x * blockDim.x + threadIdx.x;
    if (i < CT) sq[i] = 0.0f;
}

__global__ void pj_accum(const float* __restrict__ src,
                         const float* __restrict__ tgt,
                         float* __restrict__ sq) {
    int p4 = blockIdx.x * blockDim.x + threadIdx.x;   // float4 position in [0, CT4)
    if (p4 >= CT4) return;
    const float4* s = (const float4*)src;
    const float4* t = (const float4*)tgt;
    long base = (long)blockIdx.y * BPC * CT4 + p4;
    float ax = 0.f, ay = 0.f, az = 0.f, aw = 0.f;
    #pragma unroll 8
    for (int b = 0; b < BPC; ++b) {
        float4 a = s[base];
        float4 c = t[base];
        float dx = a.x - c.x, dy = a.y - c.y, dz = a.z - c.z, dw = a.w - c.w;
        ax += dx * dx; ay += dy * dy; az += dz * dz; aw += dw * dw;
        base += CT4;
    }
    atomicAdd(&sq[p4 * 4 + 0], ax);
    atomicAdd(&sq[p4 * 4 + 1], ay);
    atomicAdd(&sq[p4 * 4 + 2], az);
    atomicAdd(&sq[p4 * 4 + 3], aw);
}

__global__ void pj_finalize(const float* __restrict__ sq, float* __restrict__ out) {
    float local = 0.0f;
    // 2880 (n,t) cells; each sums 3 joint-dim rows then sqrt
    for (int i = threadIdx.x; i < NJ * TS; i += blockDim.x) {
        int n = i / TS, t = i - (i / TS) * TS;
        float s = sq[(3 * n + 0) * TS + t]
                + sq[(3 * n + 1) * TS + t]
                + sq[(3 * n + 2) * TS + t];
        local += sqrtf(s);
    }
    // wave reduce (64 lanes)
    for (int off = 32; off > 0; off >>= 1)
        local += __shfl_down(local, off, 64);
    __shared__ float red[4];
    int lane = threadIdx.x & 63, wid = threadIdx.x >> 6;
    if (lane == 0) red[wid] = local;
    __syncthreads();
    if (threadIdx.x == 0) {
        float tot = 0.f;
        int nw = blockDim.x >> 6;
        for (int w = 0; w < nw; ++w) tot += red[w];
        out[0] = tot;
    }
}

extern "C" void kernel_launch(void* const* d_in, const int* in_sizes, int n_in,
                              void* d_out, int out_size, void* d_ws, size_t ws_size,
                              hipStream_t stream) {
    const float* src = (const float*)d_in[0];
    const float* tgt = (const float*)d_in[1];
    float* sq = (float*)d_ws;          // 8640 floats = 34.6 KB scratch
    float* out = (float*)d_out;

    pj_zero<<<(CT + 255) / 256, 256, 0, stream>>>(sq);

    dim3 grid((CT4 + 255) / 256, NCHUNK);
    pj_accum<<<grid, 256, 0, stream>>>(src, tgt, sq);

    pj_finalize<<<1, 256, 0, stream>>>(sq, out);
}